// Round 1
// baseline (123.917 us; speedup 1.0000x reference)
//
#include <hip/hip_runtime.h>

// QuinticHermiteSpline: 2^24 fp32 queries, 1024 uniform knots in [0,1].
// R5: attack the ~1.8x gap to the 128 MB stream roofline (~21 us) seen in R4
//     (spline dispatch ~38.6 us = 121.0 - 2x41.2 us poison fills).
//   Theory: (a) LDS random-gather conflicts: b128 from a 16B-stride table has
//   conflict unit idx%8 -> mean 8-way (~2.9x); (b) load->store vmcnt coupling
//   in the grid-stride loop limits VMEM overlap.
//   Changes vs R4:
//   - Coefficient table as 3 contiguous float2 arrays (8B stride): three
//     ds_read_b64, start bank 2*idx%32 -> 16 columns, mean 4-way (~1.6x).
//     Same 24.5 KB LDS; 2nd/3rd reads use the DS offset: immediate.
//   - Specialized compile-time 8-trip stream loop with depth-2 NT prefetch:
//     next tile's load issues before current tile's eval+store (no store
//     drains inside the loop).
//   - __launch_bounds__(512,8): force <=64 VGPR -> 4 blocks/CU, 32 waves/CU.

#define N_KNOTS 1024
#define N_INT   1023

typedef float vfloat4 __attribute__((ext_vector_type(4)));

// cT layout (contiguous LDS block, 3*1023 float2 = 24552 B):
//   cT[i]            = {c5, c4}
//   cT[N_INT + i]    = {c3, c2}        (c2 = h2*ddyl)
//   cT[2*N_INT + i]  = {c1, c0}        (c1 = h*dyl, c0 = yl)
__device__ __forceinline__ float eval_one(float xq, const float2* cT) {
    float s = xq * 1023.0f;
    int idx = (int)s;
    idx = min(max(idx, 0), N_INT - 1);
    float t = s - (float)idx;
    float2 a = cT[idx];                // ds_read_b64, offset:0
    float2 b = cT[N_INT + idx];        // ds_read_b64, offset:8184
    float2 c = cT[2 * N_INT + idx];    // ds_read_b64, offset:16368
    float v = fmaf(a.x, t, a.y);
    v = fmaf(v, t, b.x);
    v = fmaf(v, t, b.y);
    v = fmaf(v, t, c.x);
    v = fmaf(v, t, c.y);
    return v;
}

__global__ __launch_bounds__(512, 8) void quintic_spline_fused(
    const float* __restrict__ x_new,
    const float* __restrict__ knots,
    const float* __restrict__ fv,      // [3,1024]: y, dy, ddy
    float* __restrict__ out,
    int n4)
{
    __shared__ float2 cT[3 * N_INT];   // 24552 B

    const float* __restrict__ y   = fv;
    const float* __restrict__ dy  = fv + N_KNOTS;
    const float* __restrict__ ddy = fv + 2 * N_KNOTS;

    // Per-block table build: 1023 intervals, 512 threads -> 2 each.
    // Inputs (16 KB) are L2-resident after the first few blocks.
    for (int i = threadIdx.x; i < N_INT; i += 512) {
        float xl   = knots[i];
        float h    = knots[i + 1] - xl;
        float yl   = y[i],   yr   = y[i + 1];
        float dyl  = dy[i],  dyr  = dy[i + 1];
        float ddyl = ddy[i], ddyr = ddy[i + 1];
        float dY = yr - yl;
        float h2 = 0.5f * h * h;
        float c5 =   6.0f * dY - 3.0f * h * (dyl + dyr)               + h2 * (ddyr - ddyl);
        float c4 = -15.0f * dY + h * (8.0f * dyl + 7.0f * dyr)        - h2 * (2.0f * ddyr - 3.0f * ddyl);
        float c3 =  10.0f * dY - 2.0f * h * (3.0f * dyl + 2.0f * dyr) + h2 * (ddyr - 3.0f * ddyl);
        cT[i]             = make_float2(c5, c4);
        cT[N_INT + i]     = make_float2(c3, h2 * ddyl);
        cT[2 * N_INT + i] = make_float2(h * dyl, yl);
    }
    __syncthreads();

    const vfloat4* __restrict__ x4 = (const vfloat4*)x_new;
    vfloat4* __restrict__ o4 = (vfloat4*)out;

    int tid = blockIdx.x * 512 + threadIdx.x;

    if (n4 == (1 << 22) && gridDim.x == 1024) {
        // Exactly 8 tiles of 524288 float4 each; depth-2 prefetch pipeline.
        const int STRIDE = 1 << 19;
        vfloat4 xc = __builtin_nontemporal_load(&x4[tid]);
#pragma unroll
        for (int k = 0; k < 8; ++k) {
            vfloat4 xn;
            if (k < 7) {
                xn = __builtin_nontemporal_load(&x4[tid + (k + 1) * STRIDE]);
            }
            vfloat4 r;
            r.x = eval_one(xc.x, cT);
            r.y = eval_one(xc.y, cT);
            r.z = eval_one(xc.z, cT);
            r.w = eval_one(xc.w, cT);
            __builtin_nontemporal_store(r, &o4[tid + k * STRIDE]);
            if (k < 7) xc = xn;
        }
    } else {
        // Generic fallback (any n4, any grid).
        int stride = gridDim.x * blockDim.x;
        for (int i = tid; i < n4; i += stride) {
            vfloat4 xv = __builtin_nontemporal_load(&x4[i]);
            vfloat4 r;
            r.x = eval_one(xv.x, cT);
            r.y = eval_one(xv.y, cT);
            r.z = eval_one(xv.z, cT);
            r.w = eval_one(xv.w, cT);
            __builtin_nontemporal_store(r, &o4[i]);
        }
    }
}

extern "C" void kernel_launch(void* const* d_in, const int* in_sizes, int n_in,
                              void* d_out, int out_size, void* d_ws, size_t ws_size,
                              hipStream_t stream) {
    const float* x_new = (const float*)d_in[0];
    const float* knots = (const float*)d_in[1];
    const float* fv    = (const float*)d_in[2];
    float* out = (float*)d_out;

    int n = in_sizes[0];          // 16,777,216
    int n4 = n >> 2;              // 4,194,304 = 1024 * 512 * 8

    // 1024 blocks x 512 threads: 4 blocks/CU (98 KB LDS), 32 waves/CU.
    hipLaunchKernelGGL(quintic_spline_fused, dim3(1024), dim3(512), 0, stream,
                       x_new, knots, fv, out, n4);
}

// Round 2
// 122.771 us; speedup vs baseline: 1.0093x; 1.0093x over previous
//
#include <hip/hip_runtime.h>

// QuinticHermiteSpline: 2^24 fp32 queries, 1024 uniform knots in [0,1].
// R6: latency-MLP theory. R4/R5 showed the spline dispatch stuck at ~40 us
//     (~3.2 TB/s) while poison fills hit 6.5 TB/s on the same allocations.
//     LDS-layout change (R5) was neutral -> LDS conflicts are NOT the
//     critical path (random gather does the same bank work in any layout,
//     ~10 us/CU < 21 us HBM time). Remaining gap fits a latency model:
//     ~1 outstanding 64 B load/wave x 32 waves = 2-4 KB/CU in flight, vs
//     the ~10 KB needed to cover ~1000-cyc HBM latency at 10.2 B/cyc/CU.
//   Changes vs R5:
//   - Each thread owns exactly 8 float4 (n4 = 2^22 = 2^19 threads * 8).
//     Issue all 8 nontemporal loads back-to-back into a static register
//     array, THEN eval+store each. Compiler emits counted vmcnt waits ->
//     8 loads/wave in flight; stores pipeline without drains.
//   - __launch_bounds__(512, 6): ~84 VGPR cap (32 VGPR of x-data needs
//     headroom; forcing 64 would make the scheduler sink loads and
//     collapse the pipeline). 24 waves/CU * 8 * 64 B = 12 KB/CU in flight.
//   - Keep 3x float2 LDS table (fewer result regs per gather than float4).

#define N_KNOTS 1024
#define N_INT   1023

typedef float vfloat4 __attribute__((ext_vector_type(4)));

// cT layout (contiguous LDS block, 3*1023 float2 = 24552 B):
//   cT[i]            = {c5, c4}
//   cT[N_INT + i]    = {c3, c2}        (c2 = h2*ddyl)
//   cT[2*N_INT + i]  = {c1, c0}        (c1 = h*dyl, c0 = yl)
__device__ __forceinline__ float eval_one(float xq, const float2* cT) {
    float s = xq * 1023.0f;
    int idx = (int)s;
    idx = min(max(idx, 0), N_INT - 1);
    float t = s - (float)idx;
    float2 a = cT[idx];                // ds_read_b64, offset:0
    float2 b = cT[N_INT + idx];        // ds_read_b64, offset:8184
    float2 c = cT[2 * N_INT + idx];    // ds_read_b64, offset:16368
    float v = fmaf(a.x, t, a.y);
    v = fmaf(v, t, b.x);
    v = fmaf(v, t, b.y);
    v = fmaf(v, t, c.x);
    v = fmaf(v, t, c.y);
    return v;
}

__global__ __launch_bounds__(512, 6) void quintic_spline_fused(
    const float* __restrict__ x_new,
    const float* __restrict__ knots,
    const float* __restrict__ fv,      // [3,1024]: y, dy, ddy
    float* __restrict__ out,
    int n4)
{
    __shared__ float2 cT[3 * N_INT];   // 24552 B

    const float* __restrict__ y   = fv;
    const float* __restrict__ dy  = fv + N_KNOTS;
    const float* __restrict__ ddy = fv + 2 * N_KNOTS;

    // Per-block table build: 1023 intervals, 512 threads -> 2 each.
    for (int i = threadIdx.x; i < N_INT; i += 512) {
        float xl   = knots[i];
        float h    = knots[i + 1] - xl;
        float yl   = y[i],   yr   = y[i + 1];
        float dyl  = dy[i],  dyr  = dy[i + 1];
        float ddyl = ddy[i], ddyr = ddy[i + 1];
        float dY = yr - yl;
        float h2 = 0.5f * h * h;
        float c5 =   6.0f * dY - 3.0f * h * (dyl + dyr)               + h2 * (ddyr - ddyl);
        float c4 = -15.0f * dY + h * (8.0f * dyl + 7.0f * dyr)        - h2 * (2.0f * ddyr - 3.0f * ddyl);
        float c3 =  10.0f * dY - 2.0f * h * (3.0f * dyl + 2.0f * dyr) + h2 * (ddyr - 3.0f * ddyl);
        cT[i]             = make_float2(c5, c4);
        cT[N_INT + i]     = make_float2(c3, h2 * ddyl);
        cT[2 * N_INT + i] = make_float2(h * dyl, yl);
    }
    __syncthreads();

    const vfloat4* __restrict__ x4 = (const vfloat4*)x_new;
    vfloat4* __restrict__ o4 = (vfloat4*)out;

    int tid = blockIdx.x * 512 + threadIdx.x;

    if (n4 == (1 << 22) && gridDim.x == 1024) {
        // Exactly 8 float4 per thread, 2 MB apart (spreads HBM channels).
        const int STRIDE = 1 << 19;
        vfloat4 xs[8];
#pragma unroll
        for (int k = 0; k < 8; ++k) {
            xs[k] = __builtin_nontemporal_load(&x4[tid + k * STRIDE]);
        }
#pragma unroll
        for (int k = 0; k < 8; ++k) {
            vfloat4 r;
            r.x = eval_one(xs[k].x, cT);
            r.y = eval_one(xs[k].y, cT);
            r.z = eval_one(xs[k].z, cT);
            r.w = eval_one(xs[k].w, cT);
            __builtin_nontemporal_store(r, &o4[tid + k * STRIDE]);
        }
    } else {
        // Generic fallback (any n4, any grid).
        int stride = gridDim.x * blockDim.x;
        for (int i = tid; i < n4; i += stride) {
            vfloat4 xv = __builtin_nontemporal_load(&x4[i]);
            vfloat4 r;
            r.x = eval_one(xv.x, cT);
            r.y = eval_one(xv.y, cT);
            r.z = eval_one(xv.z, cT);
            r.w = eval_one(xv.w, cT);
            __builtin_nontemporal_store(r, &o4[i]);
        }
    }
}

extern "C" void kernel_launch(void* const* d_in, const int* in_sizes, int n_in,
                              void* d_out, int out_size, void* d_ws, size_t ws_size,
                              hipStream_t stream) {
    const float* x_new = (const float*)d_in[0];
    const float* knots = (const float*)d_in[1];
    const float* fv    = (const float*)d_in[2];
    float* out = (float*)d_out;

    int n = in_sizes[0];          // 16,777,216
    int n4 = n >> 2;              // 4,194,304 = 1024 * 512 * 8

    hipLaunchKernelGGL(quintic_spline_fused, dim3(1024), dim3(512), 0, stream,
                       x_new, knots, fv, out, n4);
}

// Round 3
// 114.438 us; speedup vs baseline: 1.0828x; 1.0728x over previous
//
#include <hip/hip_runtime.h>

// QuinticHermiteSpline: 2^24 fp32 queries, 1024 uniform knots in [0,1].
// R7: DECISIVE latency-MLP test. R6 asked the compiler for an 8-deep load
//     pipeline and was neutral (~40 us, 3.3 TB/s vs 6.5 TB/s fills). Either
//     the theory is wrong, or hipcc's pressure heuristics sank the loads
//     back to depth ~2 (the guide's documented failure mode for source-level
//     pipelining). This version enforces the pipeline in inline asm:
//   - 8x global_load_dwordx4 issued as asm volatile (cannot be sunk/split),
//     SGPR base + 32-bit voffset (saddr form; offsets < 2^27, fits u32).
//   - Before eval k: s_waitcnt vmcnt(7). Invariant: exactly (8-k) loads +
//     k stores outstanding = 8; vmcnt retires in issue order, so vmcnt(7)
//     completes exactly load k. Stores are never drained in the loop.
//   - The wait asm ties "+v"(xs[k]) (blocks FMA hoisting past the wait,
//     rule #18) and clobbers "memory" (pins store k-1 before wait k, which
//     keeps the outstanding-op count invariant exact).
//   - In-flight per CU: 24 waves x 8 x 64 B = 12 KB >> ~4.6 KB needed for
//     the read side of 6.3 TB/s at ~900 cyc HBM latency.
// Prediction: spline dispatch 40 -> ~22-26 us (dur_us ~104-110) if the
// latency theory is right; unchanged if wrong (then pivot to mixed-stream /
// LDS-serialization theories).

#define N_KNOTS 1024
#define N_INT   1023

typedef float vfloat4 __attribute__((ext_vector_type(4)));

// cT layout (contiguous LDS block, 3*1023 float2 = 24552 B):
//   cT[i]            = {c5, c4}
//   cT[N_INT + i]    = {c3, c2}        (c2 = h2*ddyl)
//   cT[2*N_INT + i]  = {c1, c0}        (c1 = h*dyl, c0 = yl)
__device__ __forceinline__ float eval_one(float xq, const float2* cT) {
    float s = xq * 1023.0f;
    int idx = (int)s;
    idx = min(max(idx, 0), N_INT - 1);
    float t = s - (float)idx;
    float2 a = cT[idx];                // ds_read_b64, offset:0
    float2 b = cT[N_INT + idx];        // ds_read_b64, offset:8184
    float2 c = cT[2 * N_INT + idx];    // ds_read_b64, offset:16368
    float v = fmaf(a.x, t, a.y);
    v = fmaf(v, t, b.x);
    v = fmaf(v, t, b.y);
    v = fmaf(v, t, c.x);
    v = fmaf(v, t, c.y);
    return v;
}

__global__ __launch_bounds__(512, 6) void quintic_spline_fused(
    const float* __restrict__ x_new,
    const float* __restrict__ knots,
    const float* __restrict__ fv,      // [3,1024]: y, dy, ddy
    float* __restrict__ out,
    int n4)
{
    __shared__ float2 cT[3 * N_INT];   // 24552 B

    const float* __restrict__ y   = fv;
    const float* __restrict__ dy  = fv + N_KNOTS;
    const float* __restrict__ ddy = fv + 2 * N_KNOTS;

    // Per-block table build: 1023 intervals, 512 threads -> 2 each.
    for (int i = threadIdx.x; i < N_INT; i += 512) {
        float xl   = knots[i];
        float h    = knots[i + 1] - xl;
        float yl   = y[i],   yr   = y[i + 1];
        float dyl  = dy[i],  dyr  = dy[i + 1];
        float ddyl = ddy[i], ddyr = ddy[i + 1];
        float dY = yr - yl;
        float h2 = 0.5f * h * h;
        float c5 =   6.0f * dY - 3.0f * h * (dyl + dyr)               + h2 * (ddyr - ddyl);
        float c4 = -15.0f * dY + h * (8.0f * dyl + 7.0f * dyr)        - h2 * (2.0f * ddyr - 3.0f * ddyl);
        float c3 =  10.0f * dY - 2.0f * h * (3.0f * dyl + 2.0f * dyr) + h2 * (ddyr - 3.0f * ddyl);
        cT[i]             = make_float2(c5, c4);
        cT[N_INT + i]     = make_float2(c3, h2 * ddyl);
        cT[2 * N_INT + i] = make_float2(h * dyl, yl);
    }
    __syncthreads();
    // All build-phase vmem is drained here (compiler waits + barrier), so
    // the vmcnt bookkeeping below starts from 0 outstanding.

    int tid = blockIdx.x * 512 + threadIdx.x;

    if (n4 == (1 << 22) && gridDim.x == 1024) {
        // Exactly 8 float4 per thread, 8 MB apart; 2^19 threads.
        const uint32_t STRIDE_B = (1u << 19) * 16u;   // 8 MiB
        vfloat4* __restrict__ o4 = (vfloat4*)out;
        uint32_t off0 = (uint32_t)tid * 16u;

        vfloat4 xs[8];
        // Issue all 8 loads back-to-back; asm volatile preserves order and
        // prevents sinking. saddr form: SGPR base + u32 VGPR byte offset.
#pragma unroll
        for (int k = 0; k < 8; ++k) {
            uint32_t off = off0 + (uint32_t)k * STRIDE_B;
            asm volatile("global_load_dwordx4 %0, %1, %2"
                         : "=v"(xs[k])
                         : "v"(off), "s"(x_new));
        }
#pragma unroll
        for (int k = 0; k < 8; ++k) {
            // Outstanding here: (8-k) loads + k stores = 8. vmcnt retires in
            // issue order -> vmcnt(7) completes exactly load k. "+v" makes
            // the eval depend on the wait; "memory" pins store k-1 above.
            asm volatile("s_waitcnt vmcnt(7)"
                         : "+v"(xs[k]) :: "memory");
            vfloat4 r;
            r.x = eval_one(xs[k].x, cT);
            r.y = eval_one(xs[k].y, cT);
            r.z = eval_one(xs[k].z, cT);
            r.w = eval_one(xs[k].w, cT);
            __builtin_nontemporal_store(r, &o4[tid + k * (1 << 19)]);
        }
    } else {
        // Generic fallback (any n4, any grid).
        const vfloat4* __restrict__ x4 = (const vfloat4*)x_new;
        vfloat4* __restrict__ o4 = (vfloat4*)out;
        int stride = gridDim.x * blockDim.x;
        for (int i = tid; i < n4; i += stride) {
            vfloat4 xv = __builtin_nontemporal_load(&x4[i]);
            vfloat4 r;
            r.x = eval_one(xv.x, cT);
            r.y = eval_one(xv.y, cT);
            r.z = eval_one(xv.z, cT);
            r.w = eval_one(xv.w, cT);
            __builtin_nontemporal_store(r, &o4[i]);
        }
    }
}

extern "C" void kernel_launch(void* const* d_in, const int* in_sizes, int n_in,
                              void* d_out, int out_size, void* d_ws, size_t ws_size,
                              hipStream_t stream) {
    const float* x_new = (const float*)d_in[0];
    const float* knots = (const float*)d_in[1];
    const float* fv    = (const float*)d_in[2];
    float* out = (float*)d_out;

    int n = in_sizes[0];          // 16,777,216
    int n4 = n >> 2;              // 4,194,304 = 1024 * 512 * 8

    hipLaunchKernelGGL(quintic_spline_fused, dim3(1024), dim3(512), 0, stream,
                       x_new, knots, fv, out, n4);
}

// Round 4
// 114.021 us; speedup vs baseline: 1.0868x; 1.0037x over previous
//
#include <hip/hip_runtime.h>

// QuinticHermiteSpline: 2^24 fp32 queries, 1024 uniform knots in [0,1].
// R8: steady-state rotating load pipeline. R7 (asm-enforced one-shot 8-deep)
//     confirmed the latency-MLP theory: spline dispatch ~40 -> ~29 us. But
//     one-shot depth decays 8->1 as evals consume loads (avg ~4.5) and ends.
//     This version sustains depth ~8-9 across 16 items/thread:
//   - 512 blocks x 512 threads = 2^18 threads x 16 float4 each. Exactly
//     2 blocks/CU resident (no backfill imbalance), 16 waves/CU, 49 KB LDS.
//   - Pre-issue L0..L7; iteration k: issue L(k+8) (k<8), s_waitcnt with a
//     COUNTED vmcnt, eval, NT store. FIFO invariant gives N = 8+k (k<=7),
//     23-k (k>=8): always >=8, stores never drained in-loop.
//   - In-flight: 16 waves x ~9 x 64 B ~= 9.2 KB/CU sustained (vs ~7 KB
//     decaying in R7) -> read stream saturates; target ~6 TB/s aggregate.
//   - __launch_bounds__(512,4): VGPR cap 128. Live xs set is 9 vfloat4
//     (36 VGPR) -> no scratch spills (a spill is a hidden vmem op that
//     would corrupt the vmcnt bookkeeping).
// Prediction: spline ~29 -> 22-24 us; harness ~114 -> 107-110 us.

#define N_KNOTS 1024
#define N_INT   1023

typedef float vfloat4 __attribute__((ext_vector_type(4)));

// cT layout (contiguous LDS block, 3*1023 float2 = 24552 B):
//   cT[i]            = {c5, c4}
//   cT[N_INT + i]    = {c3, c2}        (c2 = h2*ddyl)
//   cT[2*N_INT + i]  = {c1, c0}        (c1 = h*dyl, c0 = yl)
__device__ __forceinline__ float eval_one(float xq, const float2* cT) {
    float s = xq * 1023.0f;
    int idx = (int)s;
    idx = min(max(idx, 0), N_INT - 1);
    float t = s - (float)idx;
    float2 a = cT[idx];                // ds_read_b64, offset:0
    float2 b = cT[N_INT + idx];        // ds_read_b64, offset:8184
    float2 c = cT[2 * N_INT + idx];    // ds_read_b64, offset:16368
    float v = fmaf(a.x, t, a.y);
    v = fmaf(v, t, b.x);
    v = fmaf(v, t, b.y);
    v = fmaf(v, t, c.x);
    v = fmaf(v, t, c.y);
    return v;
}

__global__ __launch_bounds__(512, 4) void quintic_spline_fused(
    const float* __restrict__ x_new,
    const float* __restrict__ knots,
    const float* __restrict__ fv,      // [3,1024]: y, dy, ddy
    float* __restrict__ out,
    int n4)
{
    __shared__ float2 cT[3 * N_INT];   // 24552 B

    const float* __restrict__ y   = fv;
    const float* __restrict__ dy  = fv + N_KNOTS;
    const float* __restrict__ ddy = fv + 2 * N_KNOTS;

    // Per-block table build: 1023 intervals, 512 threads -> 2 each.
    for (int i = threadIdx.x; i < N_INT; i += 512) {
        float xl   = knots[i];
        float h    = knots[i + 1] - xl;
        float yl   = y[i],   yr   = y[i + 1];
        float dyl  = dy[i],  dyr  = dy[i + 1];
        float ddyl = ddy[i], ddyr = ddy[i + 1];
        float dY = yr - yl;
        float h2 = 0.5f * h * h;
        float c5 =   6.0f * dY - 3.0f * h * (dyl + dyr)               + h2 * (ddyr - ddyl);
        float c4 = -15.0f * dY + h * (8.0f * dyl + 7.0f * dyr)        - h2 * (2.0f * ddyr - 3.0f * ddyl);
        float c3 =  10.0f * dY - 2.0f * h * (3.0f * dyl + 2.0f * dyr) + h2 * (ddyr - 3.0f * ddyl);
        cT[i]             = make_float2(c5, c4);
        cT[N_INT + i]     = make_float2(c3, h2 * ddyl);
        cT[2 * N_INT + i] = make_float2(h * dyl, yl);
    }
    __syncthreads();
    // Build-phase vmem fully drained at the barrier -> vmcnt starts at 0.

    int tid = blockIdx.x * 512 + threadIdx.x;

    if (n4 == (1 << 22) && gridDim.x == 512 && blockDim.x == 512) {
        // 2^18 threads x 16 float4, items 4 MiB apart.
        const uint32_t STRIDE_B = (1u << 18) * 16u;   // 4 MiB
        vfloat4* __restrict__ o4 = (vfloat4*)out;
        uint32_t off0 = (uint32_t)tid * 16u;

        vfloat4 xs[16];                 // liveness <= 9 at any point

        // Prologue: 8 loads in flight.
#pragma unroll
        for (int k = 0; k < 8; ++k) {
            uint32_t off = off0 + (uint32_t)k * STRIDE_B;
            asm volatile("global_load_dwordx4 %0, %1, %2"
                         : "=v"(xs[k])
                         : "v"(off), "s"(x_new));
        }

#pragma unroll
        for (int k = 0; k < 16; ++k) {
            // Refill: keep ~8-9 loads outstanding through the whole pass.
            if (k + 8 < 16) {
                uint32_t off = off0 + (uint32_t)(k + 8) * STRIDE_B;
                asm volatile("global_load_dwordx4 %0, %1, %2"
                             : "=v"(xs[k + 8])
                             : "v"(off), "s"(x_new));
            }
            // FIFO bookkeeping (loads+stores retire in issue order):
            // ops younger than L_k at this point = 8+k (k<=7) / 23-k (k>=8).
            // Counted wait -> completes exactly L_k; stores never drained.
            const int N = (k <= 7) ? (8 + k) : (23 - k);
            asm volatile("s_waitcnt vmcnt(%1)"
                         : "+v"(xs[k])
                         : "i"(N)
                         : "memory");
            vfloat4 r;
            r.x = eval_one(xs[k].x, cT);
            r.y = eval_one(xs[k].y, cT);
            r.z = eval_one(xs[k].z, cT);
            r.w = eval_one(xs[k].w, cT);
            __builtin_nontemporal_store(r, &o4[tid + k * (1 << 18)]);
        }
    } else {
        // Generic fallback (any n4, any grid).
        const vfloat4* __restrict__ x4 = (const vfloat4*)x_new;
        vfloat4* __restrict__ o4 = (vfloat4*)out;
        int stride = gridDim.x * blockDim.x;
        for (int i = tid; i < n4; i += stride) {
            vfloat4 xv = __builtin_nontemporal_load(&x4[i]);
            vfloat4 r;
            r.x = eval_one(xv.x, cT);
            r.y = eval_one(xv.y, cT);
            r.z = eval_one(xv.z, cT);
            r.w = eval_one(xv.w, cT);
            __builtin_nontemporal_store(r, &o4[i]);
        }
    }
}

extern "C" void kernel_launch(void* const* d_in, const int* in_sizes, int n_in,
                              void* d_out, int out_size, void* d_ws, size_t ws_size,
                              hipStream_t stream) {
    const float* x_new = (const float*)d_in[0];
    const float* knots = (const float*)d_in[1];
    const float* fv    = (const float*)d_in[2];
    float* out = (float*)d_out;

    int n = in_sizes[0];          // 16,777,216
    int n4 = n >> 2;              // 4,194,304 = 512 * 512 * 16

    // 512 blocks x 512 threads: exactly 2 blocks/CU (49 KB LDS), 16 waves/CU.
    hipLaunchKernelGGL(quintic_spline_fused, dim3(512), dim3(512), 0, stream,
                       x_new, knots, fv, out, n4);
}

// Round 5
// 113.270 us; speedup vs baseline: 1.0940x; 1.0066x over previous
//
#include <hip/hip_runtime.h>

// QuinticHermiteSpline: 2^24 fp32 queries, 1024 uniform knots in [0,1].
// R9: LDS-ring deep-MLP. R7 vs R8 isolated the law: BW ~ in-flight bytes
//     (both ~9.2 KB/CU avg -> both ~4.4 TB/s; effective loaded latency
//     ~2600 cyc, 3x idle latency). Register pipelines cannot exceed
//     ~9 KB/CU here because waves x items/thread is fixed at 256 by the
//     problem size. Fix: stage x through a per-wave LDS ring with
//     global_load_lds -- outstanding loads cost LDS slots, not VGPRs.
//   - 512 blocks x 512 threads, 16 items/thread (2 blocks/CU, 16 waves/CU).
//   - Per-wave ring: D=4 slots x 1 KB (64 lanes x 16 B). LDS = 24.5 KB
//     table + 32 KB ring = 56.5 KB/block (< 64 KB limit), 113 KB/CU.
//   - In-flight: 16 waves x 4 KB = 64 KB/CU sustained (7x R8).
//   - Per-wave FIFO (loads + NT stores, in-order vmcnt retire), iter k:
//       wait vmcnt(N_k) -> ds_read slot k%4 -> eval -> store -> refill
//     N_k = min(3,15-k) + min(k,3)  (steady 6; never 0 -> no store drains).
//     Refill is issued AFTER the slot's ds_read (WAR on same slot) and its
//     LDS write lands ~2000 cyc later -> no race. sched_barrier(0) pins it.
// Prediction: spline ~29 -> 21-23 us (4.4 -> ~6 TB/s); harness ~106-109 us.

#define N_KNOTS 1024
#define N_INT   1023
#define RING_D  4

typedef float vfloat4 __attribute__((ext_vector_type(4)));

#define AS1 __attribute__((address_space(1)))
#define AS3 __attribute__((address_space(3)))

// cT layout (contiguous LDS block, 3*1023 float2 = 24552 B):
//   cT[i]            = {c5, c4}
//   cT[N_INT + i]    = {c3, c2}        (c2 = h2*ddyl)
//   cT[2*N_INT + i]  = {c1, c0}        (c1 = h*dyl, c0 = yl)
__device__ __forceinline__ float eval_one(float xq, const float2* cT) {
    float s = xq * 1023.0f;
    int idx = (int)s;
    idx = min(max(idx, 0), N_INT - 1);
    float t = s - (float)idx;
    float2 a = cT[idx];                // ds_read_b64, offset:0
    float2 b = cT[N_INT + idx];        // ds_read_b64, offset:8184
    float2 c = cT[2 * N_INT + idx];    // ds_read_b64, offset:16368
    float v = fmaf(a.x, t, a.y);
    v = fmaf(v, t, b.x);
    v = fmaf(v, t, b.y);
    v = fmaf(v, t, c.x);
    v = fmaf(v, t, c.y);
    return v;
}

__global__ __launch_bounds__(512, 4) void quintic_spline_fused(
    const float* __restrict__ x_new,
    const float* __restrict__ knots,
    const float* __restrict__ fv,      // [3,1024]: y, dy, ddy
    float* __restrict__ out,
    int n4)
{
    __shared__ float2 cT[3 * N_INT];               // 24552 B
    __shared__ __align__(16) float ring[8][RING_D][256];  // 8 waves x 4 KB = 32768 B

    const float* __restrict__ y   = fv;
    const float* __restrict__ dy  = fv + N_KNOTS;
    const float* __restrict__ ddy = fv + 2 * N_KNOTS;

    // Per-block table build: 1023 intervals, 512 threads -> 2 each.
    for (int i = threadIdx.x; i < N_INT; i += 512) {
        float xl   = knots[i];
        float h    = knots[i + 1] - xl;
        float yl   = y[i],   yr   = y[i + 1];
        float dyl  = dy[i],  dyr  = dy[i + 1];
        float ddyl = ddy[i], ddyr = ddy[i + 1];
        float dY = yr - yl;
        float h2 = 0.5f * h * h;
        float c5 =   6.0f * dY - 3.0f * h * (dyl + dyr)               + h2 * (ddyr - ddyl);
        float c4 = -15.0f * dY + h * (8.0f * dyl + 7.0f * dyr)        - h2 * (2.0f * ddyr - 3.0f * ddyl);
        float c3 =  10.0f * dY - 2.0f * h * (3.0f * dyl + 2.0f * dyr) + h2 * (ddyr - 3.0f * ddyl);
        cT[i]             = make_float2(c5, c4);
        cT[N_INT + i]     = make_float2(c3, h2 * ddyl);
        cT[2 * N_INT + i] = make_float2(h * dyl, yl);
    }
    __syncthreads();
    // Barrier semantics drain all vmem/lgkm -> per-wave vmcnt starts at 0.

    int tid = blockIdx.x * 512 + threadIdx.x;

    if (n4 == (1 << 22) && gridDim.x == 512 && blockDim.x == 512) {
        const int w    = threadIdx.x >> 6;         // wave id, lane-uniform
        const int lane = threadIdx.x & 63;
        vfloat4* __restrict__ o4 = (vfloat4*)out;

        // Item k of this thread: float4 index tid + k*2^18 (4 MiB stride).
        // Wave's lanes are contiguous -> each global_load_lds stages a
        // contiguous 1 KB segment; lane data lands at slot + lane*16.

        // Prologue: fill the ring, 4 loads in flight per wave.
#pragma unroll
        for (int k = 0; k < RING_D; ++k) {
            const float* gsrc = x_new + ((size_t)(tid + (k << 18)) * 4);
            __builtin_amdgcn_global_load_lds(
                (AS1 const unsigned*)(const void*)gsrc,
                (AS3 unsigned*)(void*)&ring[w][k][0], 16, 0, 0);
        }

#pragma unroll
        for (int k = 0; k < 16; ++k) {
            // Ops younger than load k in this wave's vmem FIFO:
            //   loads: min(RING_D-1, 15-k); stores: min(k, RING_D-1).
            const int N = ((RING_D - 1) < (15 - k) ? (RING_D - 1) : (15 - k))
                        + (k < (RING_D - 1) ? k : (RING_D - 1));
            asm volatile("s_waitcnt vmcnt(%0)" :: "i"(N) : "memory");

            // Consume slot k%4 (ordered after the wait by the clobber).
            vfloat4 xv = *(const vfloat4*)&ring[w][k & (RING_D - 1)][lane << 2];
            vfloat4 r;
            r.x = eval_one(xv.x, cT);
            r.y = eval_one(xv.y, cT);
            r.z = eval_one(xv.z, cT);
            r.w = eval_one(xv.w, cT);
            __builtin_nontemporal_store(r, &o4[tid + (k << 18)]);

            // Refill the slot just consumed. Issued after the ds_read in
            // program order (WAR, same address); its LDS write lands at
            // data return ~2000 cyc later. sched_barrier pins the order.
            __builtin_amdgcn_sched_barrier(0);
            if (k + RING_D < 16) {
                const float* gsrc =
                    x_new + ((size_t)(tid + ((k + RING_D) << 18)) * 4);
                __builtin_amdgcn_global_load_lds(
                    (AS1 const unsigned*)(const void*)gsrc,
                    (AS3 unsigned*)(void*)&ring[w][k & (RING_D - 1)][0],
                    16, 0, 0);
            }
        }
    } else {
        // Generic fallback (any n4, any grid).
        const vfloat4* __restrict__ x4 = (const vfloat4*)x_new;
        vfloat4* __restrict__ o4 = (vfloat4*)out;
        int stride = gridDim.x * blockDim.x;
        for (int i = tid; i < n4; i += stride) {
            vfloat4 xv = __builtin_nontemporal_load(&x4[i]);
            vfloat4 r;
            r.x = eval_one(xv.x, cT);
            r.y = eval_one(xv.y, cT);
            r.z = eval_one(xv.z, cT);
            r.w = eval_one(xv.w, cT);
            __builtin_nontemporal_store(r, &o4[i]);
        }
    }
}

extern "C" void kernel_launch(void* const* d_in, const int* in_sizes, int n_in,
                              void* d_out, int out_size, void* d_ws, size_t ws_size,
                              hipStream_t stream) {
    const float* x_new = (const float*)d_in[0];
    const float* knots = (const float*)d_in[1];
    const float* fv    = (const float*)d_in[2];
    float* out = (float*)d_out;

    int n = in_sizes[0];          // 16,777,216
    int n4 = n >> 2;              // 4,194,304 = 512 * 512 * 16

    // 512 blocks x 512 threads: exactly 2 blocks/CU (56.5 KB LDS each),
    // 16 waves/CU.
    hipLaunchKernelGGL(quintic_spline_fused, dim3(512), dim3(512), 0, stream,
                       x_new, knots, fv, out, n4);
}

// Round 6
// 113.024 us; speedup vs baseline: 1.0964x; 1.0022x over previous
//
#include <hip/hip_runtime.h>

// QuinticHermiteSpline: 2^24 fp32 queries, 1024 uniform knots in [0,1].
// R10: DRAM-footprint layout. R9's 56 KB/CU in-flight (7x R8) moved BW only
//     4.4 -> ~4.9 TB/s => MLP is no longer the limiter (Little's law says
//     56 KB/CU supports >10 TB/s). Per-CU pipes (LDS ~9us, VALU ~3us,
//     TA ~3.4us) are all << the 20.8us HBM floor. Remaining difference vs
//     the 6.3 TB/s reference copy: INSTANTANEOUS FOOTPRINT. The 4 MiB
//     item-stride made all 256 CUs read/write the same 4 MiB window in
//     lockstep -> DRAM row/bank hotspotting. Fix: block-contiguous cursors.
//   - Block b owns a contiguous 128 KB region (8192 float4); iter k covers
//     its next 8 KB. 512 cursors spread uniformly over the buffer, like the
//     6.5 TB/s fills. Wave coalescing unchanged (1 KB per global_load_lds).
//   - Prologue ring loads issued BEFORE the table build (first HBM latency
//     hides under build; the barrier drains them into LDS, ready for k=0).
//   - Refill issued right after the slot's ds_read (before eval), pinned by
//     sched_barrier(0). FIFO invariant after the barrier:
//     iter j appends [L_{j+4}, S_j] -> younger-than-L_k =
//     min(k,4) stores + min(3,15-k) loads; steady N=7, never 0.
//   - LDS: 24552 (table) + 32768 (ring 8 waves x 4 x 1KB) = 57320 B,
//     2 blocks/CU, 16 waves/CU, ~64 KB/CU reads in flight.
// Prediction: spline ~26 -> 21-23 us (dur ~105-110); neutral => declare
// the mixed-stream ceiling for this pattern and stop.

#define N_KNOTS 1024
#define N_INT   1023
#define RING_D  4

typedef float vfloat4 __attribute__((ext_vector_type(4)));

#define AS1 __attribute__((address_space(1)))
#define AS3 __attribute__((address_space(3)))

// cT layout (contiguous LDS block, 3*1023 float2 = 24552 B):
//   cT[i]            = {c5, c4}
//   cT[N_INT + i]    = {c3, c2}        (c2 = h2*ddyl)
//   cT[2*N_INT + i]  = {c1, c0}        (c1 = h*dyl, c0 = yl)
__device__ __forceinline__ float eval_one(float xq, const float2* cT) {
    float s = xq * 1023.0f;
    int idx = (int)s;
    idx = min(max(idx, 0), N_INT - 1);
    float t = s - (float)idx;
    float2 a = cT[idx];                // ds_read_b64, offset:0
    float2 b = cT[N_INT + idx];        // ds_read_b64, offset:8184
    float2 c = cT[2 * N_INT + idx];    // ds_read_b64, offset:16368
    float v = fmaf(a.x, t, a.y);
    v = fmaf(v, t, b.x);
    v = fmaf(v, t, b.y);
    v = fmaf(v, t, c.x);
    v = fmaf(v, t, c.y);
    return v;
}

__global__ __launch_bounds__(512, 4) void quintic_spline_fused(
    const float* __restrict__ x_new,
    const float* __restrict__ knots,
    const float* __restrict__ fv,      // [3,1024]: y, dy, ddy
    float* __restrict__ out,
    int n4)
{
    __shared__ float2 cT[3 * N_INT];                      // 24552 B
    __shared__ __align__(16) float ring[8][RING_D][256];  // 32768 B

    const int w    = threadIdx.x >> 6;         // wave id (lane-uniform)
    const int lane = threadIdx.x & 63;

    const bool fast = (n4 == (1 << 22)) && (gridDim.x == 512)
                      && (blockDim.x == 512);

    if (fast) {
        // Issue ring prologue FIRST: 4 x 1 KB/wave global_load_lds. Their
        // HBM latency hides under the table build; the build's own loads
        // queue behind them in the same FIFO (in-order, completes first).
        uint32_t base_b = ((uint32_t)blockIdx.x * 8192u
                           + (uint32_t)threadIdx.x) * 16u;
#pragma unroll
        for (int k = 0; k < RING_D; ++k) {
            const float* gsrc =
                (const float*)((const char*)x_new + base_b + (uint32_t)k * 8192u);
            __builtin_amdgcn_global_load_lds(
                (AS1 const unsigned*)(const void*)gsrc,
                (AS3 unsigned*)(void*)&ring[w][k][0], 16, 0, 0);
        }
    }

    {
        const float* __restrict__ y   = fv;
        const float* __restrict__ dy  = fv + N_KNOTS;
        const float* __restrict__ ddy = fv + 2 * N_KNOTS;
        // Per-block table build: 1023 intervals, 512 threads -> 2 each.
        for (int i = threadIdx.x; i < N_INT; i += 512) {
            float xl   = knots[i];
            float h    = knots[i + 1] - xl;
            float yl   = y[i],   yr   = y[i + 1];
            float dyl  = dy[i],  dyr  = dy[i + 1];
            float ddyl = ddy[i], ddyr = ddy[i + 1];
            float dY = yr - yl;
            float h2 = 0.5f * h * h;
            float c5 =   6.0f * dY - 3.0f * h * (dyl + dyr)               + h2 * (ddyr - ddyl);
            float c4 = -15.0f * dY + h * (8.0f * dyl + 7.0f * dyr)        - h2 * (2.0f * ddyr - 3.0f * ddyl);
            float c3 =  10.0f * dY - 2.0f * h * (3.0f * dyl + 2.0f * dyr) + h2 * (ddyr - 3.0f * ddyl);
            cT[i]             = make_float2(c5, c4);
            cT[N_INT + i]     = make_float2(c3, h2 * ddyl);
            cT[2 * N_INT + i] = make_float2(h * dyl, yl);
        }
    }
    __syncthreads();
    // Barrier drains all vmem (prologue completed into LDS) -> vmcnt = 0.

    if (fast) {
        // Block-contiguous region: 8192 float4 per block; iter k covers
        // float4 indices base4 + k*512 (8 KB cursor step per block).
        uint32_t base4 = (uint32_t)blockIdx.x * 8192u + (uint32_t)threadIdx.x;
        vfloat4* __restrict__ o4 = (vfloat4*)out;

#pragma unroll
        for (int k = 0; k < 16; ++k) {
            // Younger-than-L_k in this wave's FIFO (iter j appends
            // [L_{j+4}, S_j] after the barrier):
            //   stores: min(k,4); loads: min(3, 15-k). Steady 7, never 0.
            // k<4: L_k completed pre-barrier; N >= current outstanding
            // (k=0:0<=3, k=1:2<=4, k=2:4<=5, k=3:6<=6) -> pass-through.
            const int N = (k < 4 ? k : 4) + ((15 - k) < 3 ? (15 - k) : 3);
            asm volatile("s_waitcnt vmcnt(%0)" :: "i"(N) : "memory");

            // Consume slot k%4 (ds_read ordered after the wait by the
            // memory clobber; lgkmcnt wait auto-inserted before the FMAs).
            vfloat4 xv = *(const vfloat4*)&ring[w][k & (RING_D - 1)][lane << 2];

            // Refill the just-read slot immediately (issue ASAP; its LDS
            // write returns from HBM far after the ds_read completes).
            if (k + RING_D < 16) {
                const float* gsrc =
                    x_new + (size_t)(base4 + (uint32_t)(k + RING_D) * 512u) * 4;
                __builtin_amdgcn_global_load_lds(
                    (AS1 const unsigned*)(const void*)gsrc,
                    (AS3 unsigned*)(void*)&ring[w][k & (RING_D - 1)][0],
                    16, 0, 0);
            }
            __builtin_amdgcn_sched_barrier(0);   // pin refill before eval/store

            vfloat4 r;
            r.x = eval_one(xv.x, cT);
            r.y = eval_one(xv.y, cT);
            r.z = eval_one(xv.z, cT);
            r.w = eval_one(xv.w, cT);
            __builtin_nontemporal_store(r, &o4[base4 + (uint32_t)k * 512u]);
        }
    } else {
        // Generic fallback (any n4, any grid).
        const vfloat4* __restrict__ x4 = (const vfloat4*)x_new;
        vfloat4* __restrict__ o4 = (vfloat4*)out;
        int tid = blockIdx.x * blockDim.x + threadIdx.x;
        int stride = gridDim.x * blockDim.x;
        for (int i = tid; i < n4; i += stride) {
            vfloat4 xv = __builtin_nontemporal_load(&x4[i]);
            vfloat4 r;
            r.x = eval_one(xv.x, cT);
            r.y = eval_one(xv.y, cT);
            r.z = eval_one(xv.z, cT);
            r.w = eval_one(xv.w, cT);
            __builtin_nontemporal_store(r, &o4[i]);
        }
    }
}

extern "C" void kernel_launch(void* const* d_in, const int* in_sizes, int n_in,
                              void* d_out, int out_size, void* d_ws, size_t ws_size,
                              hipStream_t stream) {
    const float* x_new = (const float*)d_in[0];
    const float* knots = (const float*)d_in[1];
    const float* fv    = (const float*)d_in[2];
    float* out = (float*)d_out;

    int n = in_sizes[0];          // 16,777,216
    int n4 = n >> 2;              // 4,194,304 = 512 * 8192

    // 512 blocks x 512 threads: exactly 2 blocks/CU (57.3 KB LDS each),
    // 16 waves/CU.
    hipLaunchKernelGGL(quintic_spline_fused, dim3(512), dim3(512), 0, stream,
                       x_new, knots, fv, out, n4);
}